// Round 4
// baseline (381.108 us; speedup 1.0000x reference)
//
#include <hip/hip_runtime.h>
#include <stdint.h>

#define BATCH 16
#define NQ 2000
#define NC 80
#define NG 100
#define MAX_ITERS 1000
#define MAXC 96
#define QT 64
#define TILES 32            // ceil(2000/64)
#define K1_BLOCKS (BATCH * TILES)   // 512
#define K2_BS 256
#define NW2 4
#define LISTS_STRIDE 12

// output layout (floats)
#define OFF_SEL 0
#define OFF_GTI (BATCH * NQ)                 // 32000
#define OFF_MQ (2 * BATCH * NQ)              // 64000
#define OFF_M (2 * BATCH * NQ + BATCH * NG)  // 65600

// exact replay of the reference's sequential in-place +1e5 adds
__device__ __forceinline__ float fmut(float c, int k) {
    for (int i = 0; i < k; ++i) c += 100000.0f;
    return c;
}

#define SWAPVI(av, ai, bv, bi) { float tv_ = av; av = bv; bv = tv_; int ti_ = ai; ai = bi; bi = ti_; }
#define LEXLT(v, i, V, I) ((v) < (V) || ((v) == (V) && (i) < (I)))
#define INSB(vv, ii) do { float v_ = (vv); int i_ = (ii); \
    if (LEXLT(v_, i_, bv4, bi4)) { bv4 = v_; bi4 = i_; \
        if (LEXLT(bv4, bi4, bv3, bi3)) SWAPVI(bv3, bi3, bv4, bi4); \
        if (LEXLT(bv3, bi3, bv2, bi2)) SWAPVI(bv2, bi2, bv3, bi3); \
        if (LEXLT(bv2, bi2, bv1, bi1)) SWAPVI(bv1, bi1, bv2, bi2); \
        if (LEXLT(bv1, bi1, bv0, bi0)) SWAPVI(bv0, bi0, bv1, bi1); \
    } } while (0)
#define INST(vv) do { float v_ = (vv); \
    if (v_ > t4) { t4 = v_; \
        if (t4 > t3) { float x_ = t3; t3 = t4; t4 = x_; } \
        if (t3 > t2) { float x_ = t2; t2 = t3; t3 = x_; } \
        if (t2 > t1) { float x_ = t1; t1 = t2; t2 = x_; } \
        if (t1 > t0) { float x_ = t0; t0 = t1; t1 = x_; } \
    } } while (0)

// device-scope grid barrier; all gridDim.x blocks must be co-resident
__device__ __forceinline__ void grid_barrier(int* sync, int target) {
    __syncthreads();
    __threadfence();
    if (threadIdx.x == 0) {
        __hip_atomic_fetch_add(sync, 1, __ATOMIC_ACQ_REL, __HIP_MEMORY_SCOPE_AGENT);
        while (__hip_atomic_load(sync, __ATOMIC_ACQUIRE, __HIP_MEMORY_SCOPE_AGENT) < target)
            __builtin_amdgcn_s_sleep(16);
    }
    __syncthreads();
    __threadfence();
}

// =================== K1: fg + cost (tiled) | grid barrier | dynk/bottom5 + rowargmin ===================
__global__ __launch_bounds__(256, 2) void precompute_kernel(
    const float* __restrict__ logits, const float* __restrict__ pred_boxes,
    const float* __restrict__ gt_boxes, const int* __restrict__ labels,
    const float* __restrict__ img_sz,
    float* __restrict__ costT_all,   // out+OFF_M, [b][g][q]
    float* __restrict__ rowamin,     // out+OFF_GTI (scratch, overwritten by K2)
    float* __restrict__ lists,       // ws: BATCH*NG*12 floats
    int* __restrict__ sync) {
    const int tid = threadIdx.x;

    __shared__ float ct[QT][NG + 1];                       // 25.9 KB (pad -> conflict-free col reads)
    __shared__ float s_rx1[NG], s_ry1[NG], s_rx2[NG], s_ry2[NG];   // roundtrip xyxy
    __shared__ float s_clx[NG], s_chx[NG], s_cly[NG], s_chy[NG];   // center-radius bounds
    __shared__ float s_gx1[NG], s_gy1[NG], s_gx2[NG], s_gy2[NG];   // abs xyxy
    __shared__ float s_d1[NG], s_d2[NG], s_d3[NG], s_d4[NG];       // abs/img
    __shared__ float s_ga[NG];
    __shared__ int s_lab[NG];
    __shared__ float pbx[QT][11];   // x1,y1,x2,y2,ax,ay,x1d,y1d,x2d,y2d,aA
    __shared__ unsigned fgm[QT];

    // ---------- phase 1: one 64q x 100g tile per block ----------
    {
        const int b = blockIdx.x / TILES;
        const int tile = blockIdx.x - b * TILES;
        const int q0 = tile * QT;
        const float i0 = img_sz[b * 4 + 0], i1 = img_sz[b * 4 + 1];
        const float i2 = img_sz[b * 4 + 2], i3 = img_sz[b * 4 + 3];

        if (tid < NG) {
            const float4 gt = *reinterpret_cast<const float4*>(gt_boxes + (b * NG + tid) * 4);
            float GX1 = (gt.x - 0.5f * gt.z) * i0, GY1 = (gt.y - 0.5f * gt.w) * i1;
            float GX2 = (gt.x + 0.5f * gt.z) * i2, GY2 = (gt.y + 0.5f * gt.w) * i3;
            float tcx = (GX1 + GX2) * 0.5f, tcy = (GY1 + GY2) * 0.5f;
            float tw = GX2 - GX1, th = GY2 - GY1;
            float X1 = tcx - 0.5f * tw, Y1 = tcy - 0.5f * th;
            float X2 = tcx + 0.5f * tw, Y2 = tcy + 0.5f * th;
            float w_ = X2 - X1, h_ = Y2 - Y1;
            s_rx1[tid] = X1; s_ry1[tid] = Y1; s_rx2[tid] = X2; s_ry2[tid] = Y2;
            s_clx[tid] = tcx - 2.5f * w_; s_chx[tid] = tcx + 2.5f * w_;
            s_cly[tid] = tcy - 2.5f * h_; s_chy[tid] = tcy + 2.5f * h_;
            s_gx1[tid] = GX1; s_gy1[tid] = GY1; s_gx2[tid] = GX2; s_gy2[tid] = GY2;
            s_d1[tid] = GX1 / i0; s_d2[tid] = GY1 / i1; s_d3[tid] = GX2 / i2; s_d4[tid] = GY2 / i3;
            s_ga[tid] = (GX2 - GX1) * (GY2 - GY1);
            s_lab[tid] = labels[b * NG + tid];
        }
        if (tid < QT) {
            fgm[tid] = 0;
            int q = q0 + tid;
            if (q < NQ) {
                const float4 pb = *reinterpret_cast<const float4*>(pred_boxes + (size_t)(b * NQ + q) * 4);
                float x1 = (pb.x - 0.5f * pb.z) * i0, y1 = (pb.y - 0.5f * pb.w) * i1;
                float x2 = (pb.x + 0.5f * pb.z) * i2, y2 = (pb.y + 0.5f * pb.w) * i3;
                pbx[tid][0] = x1; pbx[tid][1] = y1; pbx[tid][2] = x2; pbx[tid][3] = y2;
                pbx[tid][4] = (x1 + x2) * 0.5f; pbx[tid][5] = (y1 + y2) * 0.5f;
                pbx[tid][6] = x1 / i0; pbx[tid][7] = y1 / i1; pbx[tid][8] = x2 / i2; pbx[tid][9] = y2 / i3;
                pbx[tid][10] = (x2 - x1) * (y2 - y1);
            }
        }
        __syncthreads();

        // fg: 4-way split over g per q
        {
            int ql = tid & 63, part = tid >> 6;
            if (q0 + ql < NQ) {
                float ax = pbx[ql][4], ay = pbx[ql][5];
                bool any = false;
                for (int g = part * 25; g < part * 25 + 25; ++g) {
                    bool in_box = (ax > s_rx1[g]) && (ax < s_rx2[g]) && (ay > s_ry1[g]) && (ay < s_ry2[g]);
                    bool in_ctr = (ax > s_clx[g]) && (ax < s_chx[g]) && (ay > s_cly[g]) && (ay < s_chy[g]);
                    any = any || in_box || in_ctr;
                }
                if (any) atomicOr(&fgm[ql], 1u);
            }
        }
        __syncthreads();

        // cost: g-fastest (logits row locality), into LDS tile
        for (int e = 0; e < QT * NG / 256; ++e) {
            int idx = e * 256 + tid;
            int ql = idx / NG, g = idx - ql * NG;
            int q = q0 + ql;
            if (q < NQ) {
                float x1 = pbx[ql][0], y1 = pbx[ql][1], x2 = pbx[ql][2], y2 = pbx[ql][3];
                float ax = pbx[ql][4], ay = pbx[ql][5];
                bool in_box = (ax > s_rx1[g]) && (ax < s_rx2[g]) && (ay > s_ry1[g]) && (ay < s_ry2[g]);
                bool in_ctr = (ax > s_clx[g]) && (ax < s_chx[g]) && (ay > s_cly[g]) && (ay < s_chy[g]);
                bool in_bc = in_box && in_ctr;
                bool fgb = fgm[ql] != 0;

                float lg = logits[(size_t)(b * NQ + q) * NC + s_lab[g]];
                float p = 1.0f / (1.0f + expf(-lg));
                float neg = 0.75f * (p * p) * (-logf(1.0f - p + 1e-8f));
                float pos = 0.25f * ((1.0f - p) * (1.0f - p)) * (-logf(p + 1e-8f));
                float cc = pos - neg;

                float cb = fabsf(pbx[ql][6] - s_d1[g]);
                cb = cb + fabsf(pbx[ql][7] - s_d2[g]);
                cb = cb + fabsf(pbx[ql][8] - s_d3[g]);
                cb = cb + fabsf(pbx[ql][9] - s_d4[g]);

                float aA = pbx[ql][10];
                float GX1 = s_gx1[g], GY1 = s_gy1[g], GX2 = s_gx2[g], GY2 = s_gy2[g];
                float lx = fmaxf(x1, GX1), ly = fmaxf(y1, GY1);
                float rx = fminf(x2, GX2), ry = fminf(y2, GY2);
                float iw = fmaxf(rx - lx, 0.0f), ih = fmaxf(ry - ly, 0.0f);
                float inter = iw * ih;
                float uni = aA + s_ga[g] - inter;
                float iou = inter / uni;
                float hx1 = fminf(x1, GX1), hy1 = fminf(y1, GY1);
                float hx2 = fmaxf(x2, GX2), hy2 = fmaxf(y2, GY2);
                float hw = fmaxf(hx2 - hx1, 0.0f), hh = fmaxf(hy2 - hy1, 0.0f);
                float harea = hw * hh;
                float giou = iou - (harea - uni) / harea;

                float cost = 5.0f * cb;
                cost = cost + 2.0f * cc;
                cost = cost + 2.0f * (-giou);
                cost = cost + (in_bc ? 0.0f : 100.0f);
                cost = cost + (fgb ? 0.0f : 10000.0f);
                ct[ql][g] = cost;
            }
        }
        __syncthreads();

        // transpose-write: costT[b][g][q], q-contiguous
        float* dst = costT_all + (size_t)b * NQ * NG;
        for (int e = 0; e < QT * NG / 256; ++e) {
            int idx = e * 256 + tid;
            int g = idx >> 6, ql = idx & 63;
            int q = q0 + ql;
            if (q < NQ) dst[(size_t)g * NQ + q] = ct[ql][g];
        }
    }

    grid_barrier(sync, K1_BLOCKS);

    // ---------- phase 2a: rowargmin (coalesced) ----------
    {
        int gtid = blockIdx.x * 256 + tid;
        if (gtid < BATCH * NQ) {
            int b = gtid / NQ, q = gtid - b * NQ;
            const float* base = costT_all + (size_t)b * NQ * NG + q;
            float mv = base[0]; int mg = 0;
            for (int g = 1; g < NG; ++g) {
                float v = base[(size_t)g * NQ];
                if (v < mv) { mv = v; mg = g; }
            }
            rowamin[gtid] = (float)mg;
        }
    }

    // ---------- phase 2b: one wave per (b,g): dyn_k + bottom-5 (idx+val) ----------
    {
        int w = blockIdx.x * 4 + (tid >> 6);
        int lane = tid & 63;
        if (w < BATCH * NG) {
            int b = w / NG, g = w - b * NG;
            const float i0 = img_sz[b * 4 + 0], i1 = img_sz[b * 4 + 1];
            const float i2 = img_sz[b * 4 + 2], i3 = img_sz[b * 4 + 3];
            const float4 gt = *reinterpret_cast<const float4*>(gt_boxes + (b * NG + g) * 4);
            float GX1 = (gt.x - 0.5f * gt.z) * i0, GY1 = (gt.y - 0.5f * gt.w) * i1;
            float GX2 = (gt.x + 0.5f * gt.z) * i2, GY2 = (gt.y + 0.5f * gt.w) * i3;
            float GA = (GX2 - GX1) * (GY2 - GY1);

            const float* pbox = pred_boxes + (size_t)b * NQ * 4;
            float t0 = -INFINITY, t1 = -INFINITY, t2 = -INFINITY, t3 = -INFINITY, t4 = -INFINITY;
            for (int q = lane; q < NQ; q += 64) {
                const float4 pb = *reinterpret_cast<const float4*>(pbox + q * 4);
                float x1 = (pb.x - 0.5f * pb.z) * i0, y1 = (pb.y - 0.5f * pb.w) * i1;
                float x2 = (pb.x + 0.5f * pb.z) * i2, y2 = (pb.y + 0.5f * pb.w) * i3;
                float aA = (x2 - x1) * (y2 - y1);
                float lx = fmaxf(x1, GX1), ly = fmaxf(y1, GY1);
                float rx = fminf(x2, GX2), ry = fminf(y2, GY2);
                float iw = fmaxf(rx - lx, 0.0f), ih = fmaxf(ry - ly, 0.0f);
                float inter = iw * ih;
                float uni = aA + GA - inter;
                float iou = inter / uni;
                INST(iou);
            }
            for (int off = 1; off < 64; off <<= 1) {
                float o0 = __shfl_xor(t0, off), o1 = __shfl_xor(t1, off), o2 = __shfl_xor(t2, off);
                float o3 = __shfl_xor(t3, off), o4 = __shfl_xor(t4, off);
                INST(o0); INST(o1); INST(o2); INST(o3); INST(o4);
            }

            const float* col = costT_all + (size_t)b * NQ * NG + (size_t)g * NQ;
            float bv0 = INFINITY, bv1 = INFINITY, bv2 = INFINITY, bv3 = INFINITY, bv4 = INFINITY;
            int bi0 = 0x7fffffff, bi1 = 0x7fffffff, bi2 = 0x7fffffff, bi3 = 0x7fffffff, bi4 = 0x7fffffff;
            for (int q = lane; q < NQ; q += 64) {
                float v = col[q];
                INSB(v, q);
            }
            for (int off = 1; off < 64; off <<= 1) {
                float ov0 = __shfl_xor(bv0, off); int oi0 = __shfl_xor(bi0, off);
                float ov1 = __shfl_xor(bv1, off); int oi1 = __shfl_xor(bi1, off);
                float ov2 = __shfl_xor(bv2, off); int oi2 = __shfl_xor(bi2, off);
                float ov3 = __shfl_xor(bv3, off); int oi3 = __shfl_xor(bi3, off);
                float ov4 = __shfl_xor(bv4, off); int oi4 = __shfl_xor(bi4, off);
                INSB(ov0, oi0); INSB(ov1, oi1); INSB(ov2, oi2); INSB(ov3, oi3); INSB(ov4, oi4);
            }
            if (lane == 0) {
                float s = t0 + t1 + t2 + t3 + t4;
                int k = (int)s;
                if (k < 1) k = 1;
                float* o = lists + (size_t)w * LISTS_STRIDE;
                o[0] = (float)k;
                o[1] = (float)bi0; o[2] = (float)bi1; o[3] = (float)bi2; o[4] = (float)bi3; o[5] = (float)bi4;
                o[6] = bv0; o[7] = bv1; o[8] = bv2; o[9] = bv3; o[10] = bv4;
            }
        }
    }
}

// =================== K2: per-batch dynamic-k matching ===================
__global__ __launch_bounds__(K2_BS) void match_kernel(const float* __restrict__ lists,
                                                      float* __restrict__ out) {
    const int b = blockIdx.x;
    const int tid = threadIdx.x;
    const int wave = tid >> 6;
    const int lane = tid & 63;

    __shared__ uint32_t Msh[NQ][4];        // 32 KB
    __shared__ float crow[MAXC][NG + 1];   // 38.8 KB (padded: conflict-free row scans)
    __shared__ int n_q[NQ];                // 8 KB
    __shared__ int16_t cidx[NQ];           // 4 KB (-1 none, >=0 cached conf0, -2 uncached conf0)
    __shared__ int candq[NG][5];           // 2 KB
    __shared__ float candv[NG][5];         // 2 KB
    __shared__ uint8_t slotM[MAXC];
    __shared__ int crowq[MAXC];
    __shared__ int colcnt[NG];
    __shared__ int needscan[NG];
    __shared__ int flags[2];               // [0]=any col unmatched, [1]=has_conf
    __shared__ int nconf0, nscan;

    float* costT = out + OFF_M + (size_t)b * NQ * NG;
    float* selOut = out + OFF_SEL + b * NQ;
    float* gtiOut = out + OFF_GTI + b * NQ;
    const float* rowamin_b = out + OFF_GTI + b * NQ;
    float* mqOut = out + OFF_MQ + b * NG;

    if (tid == 0) { flags[0] = 0; flags[1] = 0; nconf0 = 0; nscan = 0; }
    for (int q = tid; q < NQ; q += K2_BS) {
        Msh[q][0] = 0; Msh[q][1] = 0; Msh[q][2] = 0; Msh[q][3] = 0;
        cidx[q] = -1; n_q[q] = 0;
    }
    __syncthreads();

    // build M + colcnt + candidate lists
    if (tid < NG) {
        const float* o = lists + (size_t)(b * NG + tid) * LISTS_STRIDE;
        int k = (int)o[0];
        int word = tid >> 5;
        uint32_t bit = 1u << (tid & 31);
        for (int j = 0; j < 5; ++j) {
            int qi = (int)o[1 + j];
            candq[tid][j] = qi;
            candv[tid][j] = o[6 + j];
            if (j < k) atomicOr(&Msh[qi][word], bit);
        }
        colcnt[tid] = k;
    }
    __syncthreads();

    // conflict0 rows -> onehot(precomputed row argmin)
    for (int q = tid; q < NQ; q += K2_BS) {
        uint4 m = *reinterpret_cast<const uint4*>(&Msh[q][0]);
        int pc = __popc(m.x) + __popc(m.y) + __popc(m.z) + __popc(m.w);
        if (pc > 1) {
            int slot = atomicAdd(&nconf0, 1);
            int c = (slot < MAXC) ? slot : -1;
            cidx[q] = (c >= 0) ? (int16_t)c : (int16_t)-2;
            if (c >= 0) crowq[c] = q;
            int mg = (int)rowamin_b[q];
            uint32_t words[4] = {m.x, m.y, m.z, m.w};
            for (int w = 0; w < 4; ++w) {
                uint32_t word = words[w];
                while (word) {
                    int bp = __ffs(word) - 1;
                    word &= word - 1;
                    atomicSub(&colcnt[w * 32 + bp], 1);
                }
                Msh[q][w] = 0;
            }
            Msh[q][mg >> 5] = 1u << (mg & 31);
            atomicAdd(&colcnt[mg], 1);
        }
    }
    __syncthreads();

    const int ncached = (nconf0 < MAXC) ? nconf0 : MAXC;
    const bool hasOvf = nconf0 > MAXC;
    // crow fill (original cost; +1e5 replayed incrementally in-loop)
    for (int i = tid; i < ncached * NG; i += K2_BS) {
        int c = i / NG, g = i - c * NG;
        crow[c][g] = costT[(size_t)g * NQ + crowq[c]];
    }
    if (tid < NG && colcnt[tid] == 0) flags[0] = 1;
    __syncthreads();

    // ---------------- while loop ----------------
    for (int it = 0; it < MAX_ITERS; ++it) {
        if (!flags[0]) break;

        // P1: matched-at-entry -> n_q++; mark cached rows
        for (int q = tid; q < NQ; q += K2_BS) {
            uint4 m = *reinterpret_cast<const uint4*>(&Msh[q][0]);
            bool mm = (m.x | m.y | m.z | m.w) != 0;
            if (mm) n_q[q]++;
            int c = cidx[q];
            if (c >= 0) slotM[c] = mm ? 1 : 0;
        }
        __syncthreads();  // B1

        // P1b: replay +1e5 on cached matched rows
        for (int i = tid; i < ncached * NG; i += K2_BS) {
            int c = i / NG, g = i - c * NG;
            if (slotM[c]) crow[c][g] += 100000.0f;
        }
        // P2a: candidate fast-path (sorted bottom-5 -> first with n==0 is exact argmin)
        if (tid < NG && colcnt[tid] == 0) {
            int g = tid;
            int win = -1;
            for (int j = 0; j < 5; ++j) {
                int qi = candq[g][j];
                if (n_q[qi] == 0) { win = qi; break; }
            }
            if (win >= 0) {
                atomicOr(&Msh[win][g >> 5], 1u << (g & 31));
                colcnt[g] = 1;
            } else {
                needscan[atomicAdd(&nscan, 1)] = g;
            }
        }
        __syncthreads();  // B2

        int ns = nscan;
        if (ns > 0) {
            // P2b: cooperative full-column scan fallback
            for (int s = wave; s < ns; s += NW2) {
                int g = needscan[s];
                const float* col = costT + (size_t)g * NQ;
                float mv = INFINITY; int mi = 0x7fffffff;
                for (int q = lane; q < NQ; q += 64) {
                    if (n_q[q] == 0) {
                        float v = col[q];
                        if (v < mv || (v == mv && q < mi)) { mv = v; mi = q; }
                    }
                }
                for (int off = 1; off < 64; off <<= 1) {
                    float ov = __shfl_xor(mv, off); int oi = __shfl_xor(mi, off);
                    if (ov < mv || (ov == mv && oi < mi)) { mv = ov; mi = oi; }
                }
                if (mi == 0x7fffffff) {  // every row penalized -> exact replay
                    for (int q = lane; q < NQ; q += 64) {
                        float v = fmut(col[q], n_q[q]);
                        if (v < mv || (v == mv && q < mi)) { mv = v; mi = q; }
                    }
                    for (int off = 1; off < 64; off <<= 1) {
                        float ov = __shfl_xor(mv, off); int oi = __shfl_xor(mi, off);
                        if (ov < mv || (ov == mv && oi < mi)) { mv = ov; mi = oi; }
                    }
                }
                if (lane == 0) {
                    atomicOr(&Msh[mi][g >> 5], 1u << (g & 31));
                    colcnt[g] = 1;
                }
            }
            __syncthreads();  // B2b (uniform: ns same for all threads)
        }

        // P3: has_conf = any row pc>1 (full scan — persistent conflicts count too)
        for (int q = tid; q < NQ; q += K2_BS) {
            uint4 m = *reinterpret_cast<const uint4*>(&Msh[q][0]);
            int pc = __popc(m.x) + __popc(m.y) + __popc(m.z) + __popc(m.w);
            if (pc > 1) flags[1] = 1;
        }
        __syncthreads();  // B3

        if (!flags[1]) break;  // no conflict -> no column can unmatch -> cond false

        // P4: reset ALL conflict0 rows to onehot(argmin of current mutated row)
        if (tid == 0) { flags[1] = 0; nscan = 0; flags[0] = 0; }
        for (int c = tid; c < ncached; c += K2_BS) {
            int q = crowq[c];
            float mv = crow[c][0]; int mg = 0;
            for (int g = 1; g < NG; ++g) { float v = crow[c][g]; if (v < mv) { mv = v; mg = g; } }
            int keepw = mg >> 5;
            uint32_t keepb = 1u << (mg & 31);
            for (int w = 0; w < 4; ++w) {
                uint32_t word = Msh[q][w];
                uint32_t keep = (w == keepw) ? keepb : 0u;
                uint32_t toclear = word & ~keep;
                while (toclear) {
                    int bp = __ffs(toclear) - 1;
                    toclear &= toclear - 1;
                    atomicSub(&colcnt[w * 32 + bp], 1);
                }
                if (keep && !(word & keep)) atomicAdd(&colcnt[mg], 1);
                Msh[q][w] = keep;
            }
        }
        if (hasOvf) {
            for (int q = tid; q < NQ; q += K2_BS) {
                if (cidx[q] != -2) continue;
                int k = n_q[q];
                float mv = fmut(costT[q], k); int mg = 0;
                for (int g = 1; g < NG; ++g) {
                    float v = fmut(costT[(size_t)g * NQ + q], k);
                    if (v < mv) { mv = v; mg = g; }
                }
                int keepw = mg >> 5;
                uint32_t keepb = 1u << (mg & 31);
                for (int w = 0; w < 4; ++w) {
                    uint32_t word = Msh[q][w];
                    uint32_t keep = (w == keepw) ? keepb : 0u;
                    uint32_t toclear = word & ~keep;
                    while (toclear) {
                        int bp = __ffs(toclear) - 1;
                        toclear &= toclear - 1;
                        atomicSub(&colcnt[w * 32 + bp], 1);
                    }
                    if (keep && !(word & keep)) atomicAdd(&colcnt[mg], 1);
                    Msh[q][w] = keep;
                }
            }
        }
        __syncthreads();  // B4

        // P5: loop condition
        if (tid < NG && colcnt[tid] == 0) flags[0] = 1;
        __syncthreads();  // B5
    }

    // matched_qid: argmin_q of (M ? mutated cost : 1e30)
    for (int g = wave; g < NG; g += NW2) {
        int word = g >> 5;
        uint32_t bit = 1u << (g & 31);
        const float* col = costT + (size_t)g * NQ;
        float mv = INFINITY; int mi = 0x7fffffff;
        for (int q = lane; q < NQ; q += 64) {
            float v = 1e30f;
            if (Msh[q][word] & bit) {
                int c = cidx[q];
                v = (c >= 0) ? crow[c][g] : fmut(col[q], n_q[q]);
            }
            if (v < mv || (v == mv && q < mi)) { mv = v; mi = q; }
        }
        for (int off = 1; off < 64; off <<= 1) {
            float ov = __shfl_xor(mv, off); int oi = __shfl_xor(mi, off);
            if (ov < mv || (ov == mv && oi < mi)) { mv = ov; mi = oi; }
        }
        if (lane == 0) mqOut[g] = (float)mi;
    }
    // selected / gt_idx
    for (int q = tid; q < NQ; q += K2_BS) {
        uint4 m = *reinterpret_cast<const uint4*>(&Msh[q][0]);
        selOut[q] = (m.x | m.y | m.z | m.w) ? 1.0f : 0.0f;
        int gi = 0;
        if (m.x) gi = __ffs(m.x) - 1;
        else if (m.y) gi = 32 + __ffs(m.y) - 1;
        else if (m.z) gi = 64 + __ffs(m.z) - 1;
        else if (m.w) gi = 96 + __ffs(m.w) - 1;
        gtiOut[q] = (float)gi;
    }
    __syncthreads();  // all costT reads done before overwrite
    // M output (row-major [q][g]) overwrites costT
    for (int i = tid; i < NQ * NG; i += K2_BS) {
        int q = i / NG;
        int g = i - q * NG;
        costT[i] = (Msh[q][g >> 5] & (1u << (g & 31))) ? 1.0f : 0.0f;
    }
}

extern "C" void kernel_launch(void* const* d_in, const int* in_sizes, int n_in,
                              void* d_out, int out_size, void* d_ws, size_t ws_size,
                              hipStream_t stream) {
    const float* logits = (const float*)d_in[0];
    const float* pboxes = (const float*)d_in[1];
    const float* gboxes = (const float*)d_in[2];
    const int* labels = (const int*)d_in[3];
    const float* img = (const float*)d_in[4];
    float* out = (float*)d_out;
    int* sync = (int*)d_ws;
    float* lists = (float*)((char*)d_ws + 64);  // BATCH*NG*12 floats = 76.8 KB

    hipMemsetAsync(d_ws, 0, 64, stream);
    precompute_kernel<<<K1_BLOCKS, 256, 0, stream>>>(
        logits, pboxes, gboxes, labels, img,
        out + OFF_M, out + OFF_GTI, lists, sync);
    match_kernel<<<BATCH, K2_BS, 0, stream>>>(lists, out);
}

// Round 5
// 185.751 us; speedup vs baseline: 2.0517x; 2.0517x over previous
//
#include <hip/hip_runtime.h>
#include <stdint.h>

#define BATCH 16
#define NQ 2000
#define NC 80
#define NG 100
#define MAX_ITERS 1000
#define MAXC 96
#define QT 64
#define TILES 32                     // ceil(2000/64)
#define K1_BLOCKS (BATCH * TILES)    // 512
#define K3_BS 1024
#define NW3 16
#define NCAND 12
#define LSTRIDE 13                   // k + 12 candidate indices

// output layout (floats)
#define OFF_SEL 0
#define OFF_GTI (BATCH * NQ)                 // 32000
#define OFF_MQ (2 * BATCH * NQ)              // 64000
#define OFF_M (2 * BATCH * NQ + BATCH * NG)  // 65600

// exact replay of the reference's sequential in-place +1e5 adds
__device__ __forceinline__ float fmut(float c, int k) {
    for (int i = 0; i < k; ++i) c += 100000.0f;
    return c;
}

#define SWAPVI(av, ai, bv, bi) { float tv_ = av; av = bv; bv = tv_; int ti_ = ai; ai = bi; bi = ti_; }
#define LEXLT(v, i, V, I) ((v) < (V) || ((v) == (V) && (i) < (I)))
#define INST(vv) do { float v_ = (vv); \
    if (v_ > t4) { t4 = v_; \
        if (t4 > t3) { float x_ = t3; t3 = t4; t4 = x_; } \
        if (t3 > t2) { float x_ = t2; t2 = t3; t3 = x_; } \
        if (t2 > t1) { float x_ = t1; t1 = t2; t2 = x_; } \
        if (t1 > t0) { float x_ = t0; t0 = t1; t1 = x_; } \
    } } while (0)
// sorted bottom-12 insertion, tail-guarded
#define INS12(vv, ii) do { float v_ = (vv); int i_ = (ii); \
    if (LEXLT(v_, i_, cv11, ci11)) { cv11 = v_; ci11 = i_; \
        if (LEXLT(cv11, ci11, cv10, ci10)) SWAPVI(cv10, ci10, cv11, ci11); \
        if (LEXLT(cv10, ci10, cv9, ci9)) SWAPVI(cv9, ci9, cv10, ci10); \
        if (LEXLT(cv9, ci9, cv8, ci8)) SWAPVI(cv8, ci8, cv9, ci9); \
        if (LEXLT(cv8, ci8, cv7, ci7)) SWAPVI(cv7, ci7, cv8, ci8); \
        if (LEXLT(cv7, ci7, cv6, ci6)) SWAPVI(cv6, ci6, cv7, ci7); \
        if (LEXLT(cv6, ci6, cv5, ci5)) SWAPVI(cv5, ci5, cv6, ci6); \
        if (LEXLT(cv5, ci5, cv4, ci4)) SWAPVI(cv4, ci4, cv5, ci5); \
        if (LEXLT(cv4, ci4, cv3, ci3)) SWAPVI(cv3, ci3, cv4, ci4); \
        if (LEXLT(cv3, ci3, cv2, ci2)) SWAPVI(cv2, ci2, cv3, ci3); \
        if (LEXLT(cv2, ci2, cv1, ci1)) SWAPVI(cv1, ci1, cv2, ci2); \
        if (LEXLT(cv1, ci1, cv0, ci0)) SWAPVI(cv0, ci0, cv1, ci1); \
    } } while (0)

// =================== K1: fused fg + cost, tiled, transposed write ===================
__global__ __launch_bounds__(256) void fgcost_kernel(
    const float* __restrict__ logits, const float* __restrict__ pred_boxes,
    const float* __restrict__ gt_boxes, const int* __restrict__ labels,
    const float* __restrict__ img_sz, float* __restrict__ costT_all) {
    const int tid = threadIdx.x;
    const int b = blockIdx.x / TILES;
    const int tile = blockIdx.x - b * TILES;
    const int q0 = tile * QT;

    __shared__ float ct[QT][NG + 1];
    __shared__ float s_rx1[NG], s_ry1[NG], s_rx2[NG], s_ry2[NG];
    __shared__ float s_clx[NG], s_chx[NG], s_cly[NG], s_chy[NG];
    __shared__ float s_gx1[NG], s_gy1[NG], s_gx2[NG], s_gy2[NG];
    __shared__ float s_d1[NG], s_d2[NG], s_d3[NG], s_d4[NG];
    __shared__ float s_ga[NG];
    __shared__ int s_lab[NG];
    __shared__ float pbx[QT][11];
    __shared__ unsigned fgm[QT];

    const float i0 = img_sz[b * 4 + 0], i1 = img_sz[b * 4 + 1];
    const float i2 = img_sz[b * 4 + 2], i3 = img_sz[b * 4 + 3];

    if (tid < NG) {
        const float4 gt = *reinterpret_cast<const float4*>(gt_boxes + (b * NG + tid) * 4);
        float GX1 = (gt.x - 0.5f * gt.z) * i0, GY1 = (gt.y - 0.5f * gt.w) * i1;
        float GX2 = (gt.x + 0.5f * gt.z) * i2, GY2 = (gt.y + 0.5f * gt.w) * i3;
        float tcx = (GX1 + GX2) * 0.5f, tcy = (GY1 + GY2) * 0.5f;
        float tw = GX2 - GX1, th = GY2 - GY1;
        float X1 = tcx - 0.5f * tw, Y1 = tcy - 0.5f * th;
        float X2 = tcx + 0.5f * tw, Y2 = tcy + 0.5f * th;
        float w_ = X2 - X1, h_ = Y2 - Y1;
        s_rx1[tid] = X1; s_ry1[tid] = Y1; s_rx2[tid] = X2; s_ry2[tid] = Y2;
        s_clx[tid] = tcx - 2.5f * w_; s_chx[tid] = tcx + 2.5f * w_;
        s_cly[tid] = tcy - 2.5f * h_; s_chy[tid] = tcy + 2.5f * h_;
        s_gx1[tid] = GX1; s_gy1[tid] = GY1; s_gx2[tid] = GX2; s_gy2[tid] = GY2;
        s_d1[tid] = GX1 / i0; s_d2[tid] = GY1 / i1; s_d3[tid] = GX2 / i2; s_d4[tid] = GY2 / i3;
        s_ga[tid] = (GX2 - GX1) * (GY2 - GY1);
        s_lab[tid] = labels[b * NG + tid];
    }
    if (tid < QT) {
        fgm[tid] = 0;
        int q = q0 + tid;
        if (q < NQ) {
            const float4 pb = *reinterpret_cast<const float4*>(pred_boxes + (size_t)(b * NQ + q) * 4);
            float x1 = (pb.x - 0.5f * pb.z) * i0, y1 = (pb.y - 0.5f * pb.w) * i1;
            float x2 = (pb.x + 0.5f * pb.z) * i2, y2 = (pb.y + 0.5f * pb.w) * i3;
            pbx[tid][0] = x1; pbx[tid][1] = y1; pbx[tid][2] = x2; pbx[tid][3] = y2;
            pbx[tid][4] = (x1 + x2) * 0.5f; pbx[tid][5] = (y1 + y2) * 0.5f;
            pbx[tid][6] = x1 / i0; pbx[tid][7] = y1 / i1; pbx[tid][8] = x2 / i2; pbx[tid][9] = y2 / i3;
            pbx[tid][10] = (x2 - x1) * (y2 - y1);
        }
    }
    __syncthreads();

    // fg: 4-way split over g per q
    {
        int ql = tid & 63, part = tid >> 6;
        if (q0 + ql < NQ) {
            float ax = pbx[ql][4], ay = pbx[ql][5];
            bool any = false;
            for (int g = part * 25; g < part * 25 + 25; ++g) {
                bool in_box = (ax > s_rx1[g]) && (ax < s_rx2[g]) && (ay > s_ry1[g]) && (ay < s_ry2[g]);
                bool in_ctr = (ax > s_clx[g]) && (ax < s_chx[g]) && (ay > s_cly[g]) && (ay < s_chy[g]);
                any = any || in_box || in_ctr;
            }
            if (any) atomicOr(&fgm[ql], 1u);
        }
    }
    __syncthreads();

    for (int e = 0; e < QT * NG / 256; ++e) {
        int idx = e * 256 + tid;
        int ql = idx / NG, g = idx - ql * NG;
        int q = q0 + ql;
        if (q < NQ) {
            float x1 = pbx[ql][0], y1 = pbx[ql][1], x2 = pbx[ql][2], y2 = pbx[ql][3];
            float ax = pbx[ql][4], ay = pbx[ql][5];
            bool in_box = (ax > s_rx1[g]) && (ax < s_rx2[g]) && (ay > s_ry1[g]) && (ay < s_ry2[g]);
            bool in_ctr = (ax > s_clx[g]) && (ax < s_chx[g]) && (ay > s_cly[g]) && (ay < s_chy[g]);
            bool in_bc = in_box && in_ctr;
            bool fgb = fgm[ql] != 0;

            float lg = logits[(size_t)(b * NQ + q) * NC + s_lab[g]];
            float p = 1.0f / (1.0f + expf(-lg));
            float neg = 0.75f * (p * p) * (-logf(1.0f - p + 1e-8f));
            float pos = 0.25f * ((1.0f - p) * (1.0f - p)) * (-logf(p + 1e-8f));
            float cc = pos - neg;

            float cb = fabsf(pbx[ql][6] - s_d1[g]);
            cb = cb + fabsf(pbx[ql][7] - s_d2[g]);
            cb = cb + fabsf(pbx[ql][8] - s_d3[g]);
            cb = cb + fabsf(pbx[ql][9] - s_d4[g]);

            float aA = pbx[ql][10];
            float GX1 = s_gx1[g], GY1 = s_gy1[g], GX2 = s_gx2[g], GY2 = s_gy2[g];
            float lx = fmaxf(x1, GX1), ly = fmaxf(y1, GY1);
            float rx = fminf(x2, GX2), ry = fminf(y2, GY2);
            float iw = fmaxf(rx - lx, 0.0f), ih = fmaxf(ry - ly, 0.0f);
            float inter = iw * ih;
            float uni = aA + s_ga[g] - inter;
            float iou = inter / uni;
            float hx1 = fminf(x1, GX1), hy1 = fminf(y1, GY1);
            float hx2 = fmaxf(x2, GX2), hy2 = fmaxf(y2, GY2);
            float hw = fmaxf(hx2 - hx1, 0.0f), hh = fmaxf(hy2 - hy1, 0.0f);
            float harea = hw * hh;
            float giou = iou - (harea - uni) / harea;

            float cost = 5.0f * cb;
            cost = cost + 2.0f * cc;
            cost = cost + 2.0f * (-giou);
            cost = cost + (in_bc ? 0.0f : 100.0f);
            cost = cost + (fgb ? 0.0f : 10000.0f);
            ct[ql][g] = cost;
        }
    }
    __syncthreads();

    float* dst = costT_all + (size_t)b * NQ * NG;
    for (int e = 0; e < QT * NG / 256; ++e) {
        int idx = e * 256 + tid;
        int g = idx >> 6, ql = idx & 63;
        int q = q0 + ql;
        if (q < NQ) dst[(size_t)g * NQ + q] = ct[ql][g];
    }
}

// =================== K2: dynk + bottom-12 (blocks 0..399) | rowargmin (blocks 400..524) ===================
__global__ __launch_bounds__(256) void init_kernel(const float* __restrict__ pred_boxes,
                                                   const float* __restrict__ gt_boxes,
                                                   const float* __restrict__ img_sz,
                                                   const float* __restrict__ costT_all,
                                                   float* __restrict__ lists,
                                                   float* __restrict__ rowamin) {
    const int tid = threadIdx.x;
    if (blockIdx.x >= 400) {
        // rowargmin: one thread per (b,q)
        int gtid = (blockIdx.x - 400) * 256 + tid;
        if (gtid < BATCH * NQ) {
            int b = gtid / NQ, q = gtid - b * NQ;
            const float* base = costT_all + (size_t)b * NQ * NG + q;
            float mv = base[0]; int mg = 0;
            for (int g = 1; g < NG; ++g) {
                float v = base[(size_t)g * NQ];
                if (v < mv) { mv = v; mg = g; }
            }
            rowamin[gtid] = (float)mg;
        }
        return;
    }
    // dynk + bottom-12: one wave per (b,g)
    int w = blockIdx.x * 4 + (tid >> 6);
    int lane = tid & 63;
    int b = w / NG, g = w - b * NG;

    const float i0 = img_sz[b * 4 + 0], i1 = img_sz[b * 4 + 1];
    const float i2 = img_sz[b * 4 + 2], i3 = img_sz[b * 4 + 3];
    const float4 gt = *reinterpret_cast<const float4*>(gt_boxes + (b * NG + g) * 4);
    float GX1 = (gt.x - 0.5f * gt.z) * i0, GY1 = (gt.y - 0.5f * gt.w) * i1;
    float GX2 = (gt.x + 0.5f * gt.z) * i2, GY2 = (gt.y + 0.5f * gt.w) * i3;
    float GA = (GX2 - GX1) * (GY2 - GY1);

    // top-5 IoU
    const float* pbox = pred_boxes + (size_t)b * NQ * 4;
    float t0 = -INFINITY, t1 = -INFINITY, t2 = -INFINITY, t3 = -INFINITY, t4 = -INFINITY;
    for (int q = lane; q < NQ; q += 64) {
        const float4 pb = *reinterpret_cast<const float4*>(pbox + q * 4);
        float x1 = (pb.x - 0.5f * pb.z) * i0, y1 = (pb.y - 0.5f * pb.w) * i1;
        float x2 = (pb.x + 0.5f * pb.z) * i2, y2 = (pb.y + 0.5f * pb.w) * i3;
        float aA = (x2 - x1) * (y2 - y1);
        float lx = fmaxf(x1, GX1), ly = fmaxf(y1, GY1);
        float rx = fminf(x2, GX2), ry = fminf(y2, GY2);
        float iw = fmaxf(rx - lx, 0.0f), ih = fmaxf(ry - ly, 0.0f);
        float inter = iw * ih;
        float uni = aA + GA - inter;
        float iou = inter / uni;
        INST(iou);
    }
    for (int off = 1; off < 64; off <<= 1) {
        float o0 = __shfl_xor(t0, off), o1 = __shfl_xor(t1, off), o2 = __shfl_xor(t2, off);
        float o3 = __shfl_xor(t3, off), o4 = __shfl_xor(t4, off);
        INST(o0); INST(o1); INST(o2); INST(o3); INST(o4);
    }

    // sorted bottom-12 of the column (lex (cost, q))
    const float* col = costT_all + (size_t)b * NQ * NG + (size_t)g * NQ;
    float cv0 = INFINITY, cv1 = INFINITY, cv2 = INFINITY, cv3 = INFINITY, cv4 = INFINITY, cv5 = INFINITY;
    float cv6 = INFINITY, cv7 = INFINITY, cv8 = INFINITY, cv9 = INFINITY, cv10 = INFINITY, cv11 = INFINITY;
    int ci0 = 0x7fffffff, ci1 = 0x7fffffff, ci2 = 0x7fffffff, ci3 = 0x7fffffff, ci4 = 0x7fffffff, ci5 = 0x7fffffff;
    int ci6 = 0x7fffffff, ci7 = 0x7fffffff, ci8 = 0x7fffffff, ci9 = 0x7fffffff, ci10 = 0x7fffffff, ci11 = 0x7fffffff;
    for (int q = lane; q < NQ; q += 64) {
        float v = col[q];
        INS12(v, q);
    }
    for (int off = 1; off < 64; off <<= 1) {
        float w0 = __shfl_xor(cv0, off), w1 = __shfl_xor(cv1, off), w2 = __shfl_xor(cv2, off);
        float w3 = __shfl_xor(cv3, off), w4 = __shfl_xor(cv4, off), w5 = __shfl_xor(cv5, off);
        float w6 = __shfl_xor(cv6, off), w7 = __shfl_xor(cv7, off), w8 = __shfl_xor(cv8, off);
        float w9 = __shfl_xor(cv9, off), w10 = __shfl_xor(cv10, off), w11 = __shfl_xor(cv11, off);
        int j0 = __shfl_xor(ci0, off), j1 = __shfl_xor(ci1, off), j2 = __shfl_xor(ci2, off);
        int j3 = __shfl_xor(ci3, off), j4 = __shfl_xor(ci4, off), j5 = __shfl_xor(ci5, off);
        int j6 = __shfl_xor(ci6, off), j7 = __shfl_xor(ci7, off), j8 = __shfl_xor(ci8, off);
        int j9 = __shfl_xor(ci9, off), j10 = __shfl_xor(ci10, off), j11 = __shfl_xor(ci11, off);
        INS12(w0, j0); INS12(w1, j1); INS12(w2, j2); INS12(w3, j3); INS12(w4, j4); INS12(w5, j5);
        INS12(w6, j6); INS12(w7, j7); INS12(w8, j8); INS12(w9, j9); INS12(w10, j10); INS12(w11, j11);
    }

    if (lane == 0) {
        float s = t0 + t1 + t2 + t3 + t4;
        int k = (int)s;
        if (k < 1) k = 1;
        float* o = lists + (size_t)w * LSTRIDE;
        o[0] = (float)k;
        o[1] = (float)ci0; o[2] = (float)ci1; o[3] = (float)ci2; o[4] = (float)ci3;
        o[5] = (float)ci4; o[6] = (float)ci5; o[7] = (float)ci6; o[8] = (float)ci7;
        o[9] = (float)ci8; o[10] = (float)ci9; o[11] = (float)ci10; o[12] = (float)ci11;
    }
}

// =================== K3: per-batch dynamic-k matching ===================
__global__ __launch_bounds__(K3_BS) void match_kernel(const float* __restrict__ lists,
                                                      float* __restrict__ out) {
    const int b = blockIdx.x;
    const int tid = threadIdx.x;
    const int wave = tid >> 6;
    const int lane = tid & 63;

    __shared__ uint32_t Msh[NQ][4];        // 32 KB
    __shared__ float crow[MAXC][NG + 1];   // 38.8 KB padded
    __shared__ int n_q[NQ];                // 8 KB
    __shared__ int16_t cidx[NQ];           // 4 KB  (-1 none, >=0 cached conf0, -2 uncached conf0)
    __shared__ int candq[NG][NCAND];       // 4.8 KB
    __shared__ uint8_t slotM[MAXC];
    __shared__ int crowq[MAXC];
    __shared__ int colcnt[NG];
    __shared__ int needscan[NG];
    __shared__ int flags[2];               // [0]=any col unmatched, [1]=has_conf
    __shared__ int nconf0, nscan;

    float* costT = out + OFF_M + (size_t)b * NQ * NG;
    float* selOut = out + OFF_SEL + b * NQ;
    float* gtiOut = out + OFF_GTI + b * NQ;
    const float* rowamin_b = out + OFF_GTI + b * NQ;
    float* mqOut = out + OFF_MQ + b * NG;

    if (tid == 0) { flags[0] = 0; flags[1] = 0; nconf0 = 0; nscan = 0; }
    for (int q = tid; q < NQ; q += K3_BS) {
        Msh[q][0] = 0; Msh[q][1] = 0; Msh[q][2] = 0; Msh[q][3] = 0;
        cidx[q] = -1; n_q[q] = 0;
    }
    __syncthreads();

    // build M + colcnt + candidate lists
    if (tid < NG) {
        const float* o = lists + (size_t)(b * NG + tid) * LSTRIDE;
        int k = (int)o[0];
        int word = tid >> 5;
        uint32_t bit = 1u << (tid & 31);
        for (int j = 0; j < NCAND; ++j) candq[tid][j] = (int)o[1 + j];
        for (int j = 0; j < 5; ++j)
            if (j < k) atomicOr(&Msh[candq[tid][j]][word], bit);
        colcnt[tid] = k;
    }
    __syncthreads();

    // conflict0 rows -> onehot(precomputed row argmin)
    for (int q = tid; q < NQ; q += K3_BS) {
        uint4 m = *reinterpret_cast<const uint4*>(&Msh[q][0]);
        int pc = __popc(m.x) + __popc(m.y) + __popc(m.z) + __popc(m.w);
        if (pc > 1) {
            int slot = atomicAdd(&nconf0, 1);
            int c = (slot < MAXC) ? slot : -1;
            cidx[q] = (c >= 0) ? (int16_t)c : (int16_t)-2;
            if (c >= 0) crowq[c] = q;
            int mg = (int)rowamin_b[q];
            uint32_t words[4] = {m.x, m.y, m.z, m.w};
            for (int w = 0; w < 4; ++w) {
                uint32_t word = words[w];
                while (word) {
                    int bp = __ffs(word) - 1;
                    word &= word - 1;
                    atomicSub(&colcnt[w * 32 + bp], 1);
                }
                Msh[q][w] = 0;
            }
            Msh[q][mg >> 5] = 1u << (mg & 31);
            atomicAdd(&colcnt[mg], 1);
        }
    }
    __syncthreads();

    const int ncached = (nconf0 < MAXC) ? nconf0 : MAXC;
    const bool hasOvf = nconf0 > MAXC;
    for (int i = tid; i < ncached * NG; i += K3_BS) {
        int c = i / NG, g = i - c * NG;
        crow[c][g] = costT[(size_t)g * NQ + crowq[c]];
    }
    if (tid < NG && colcnt[tid] == 0) flags[0] = 1;
    __syncthreads();

    // ---------------- while loop ----------------
    for (int it = 0; it < MAX_ITERS; ++it) {
        if (!flags[0]) break;

        // P1: matched-at-entry -> n_q++; mark cached rows
        for (int q = tid; q < NQ; q += K3_BS) {
            uint4 m = *reinterpret_cast<const uint4*>(&Msh[q][0]);
            bool mm = (m.x | m.y | m.z | m.w) != 0;
            if (mm) n_q[q]++;
            int c = cidx[q];
            if (c >= 0) slotM[c] = mm ? 1 : 0;
        }
        __syncthreads();  // B1

        // P1b: replay +1e5 on cached matched rows
        for (int i = tid; i < ncached * NG; i += K3_BS) {
            int c = i / NG, g = i - c * NG;
            if (slotM[c]) crow[c][g] += 100000.0f;
        }
        // P2a: candidate fast path — first bottom-12 candidate with n==0 is the exact argmin
        if (tid < NG && colcnt[tid] == 0) {
            int g = tid;
            int win = -1;
            for (int j = 0; j < NCAND; ++j) {
                int qi = candq[g][j];
                if (n_q[qi] == 0) { win = qi; break; }
            }
            if (win >= 0) {
                atomicOr(&Msh[win][g >> 5], 1u << (g & 31));
                colcnt[g] = 1;
            } else {
                needscan[atomicAdd(&nscan, 1)] = g;
            }
        }
        __syncthreads();  // B2

        int ns = nscan;
        if (ns > 0) {
            for (int s = wave; s < ns; s += NW3) {
                int g = needscan[s];
                const float* col = costT + (size_t)g * NQ;
                float mv = INFINITY; int mi = 0x7fffffff;
                for (int q = lane; q < NQ; q += 64) {
                    if (n_q[q] == 0) {
                        float v = col[q];
                        if (v < mv || (v == mv && q < mi)) { mv = v; mi = q; }
                    }
                }
                for (int off = 1; off < 64; off <<= 1) {
                    float ov = __shfl_xor(mv, off); int oi = __shfl_xor(mi, off);
                    if (ov < mv || (ov == mv && oi < mi)) { mv = ov; mi = oi; }
                }
                if (mi == 0x7fffffff) {  // every row penalized -> exact replay
                    for (int q = lane; q < NQ; q += 64) {
                        float v = fmut(col[q], n_q[q]);
                        if (v < mv || (v == mv && q < mi)) { mv = v; mi = q; }
                    }
                    for (int off = 1; off < 64; off <<= 1) {
                        float ov = __shfl_xor(mv, off); int oi = __shfl_xor(mi, off);
                        if (ov < mv || (ov == mv && oi < mi)) { mv = ov; mi = oi; }
                    }
                }
                if (lane == 0) {
                    atomicOr(&Msh[mi][g >> 5], 1u << (g & 31));
                    colcnt[g] = 1;
                }
            }
            __syncthreads();  // B2b (ns uniform)
        }

        // P3: has_conf
        for (int q = tid; q < NQ; q += K3_BS) {
            uint4 m = *reinterpret_cast<const uint4*>(&Msh[q][0]);
            int pc = __popc(m.x) + __popc(m.y) + __popc(m.z) + __popc(m.w);
            if (pc > 1) flags[1] = 1;
        }
        __syncthreads();  // B3
        int hc = flags[1];
        __syncthreads();  // B3b — all reads done before reset
        if (!hc) break;   // no conflict -> all columns matched -> loop would exit

        if (tid == 0) { flags[1] = 0; nscan = 0; flags[0] = 0; }
        // P4: reset ALL conflict0 rows to onehot(argmin of current mutated row)
        for (int c = tid; c < ncached; c += K3_BS) {
            int q = crowq[c];
            float mv = crow[c][0]; int mg = 0;
            for (int g = 1; g < NG; ++g) { float v = crow[c][g]; if (v < mv) { mv = v; mg = g; } }
            int keepw = mg >> 5;
            uint32_t keepb = 1u << (mg & 31);
            for (int w = 0; w < 4; ++w) {
                uint32_t word = Msh[q][w];
                uint32_t keep = (w == keepw) ? keepb : 0u;
                uint32_t toclear = word & ~keep;
                while (toclear) {
                    int bp = __ffs(toclear) - 1;
                    toclear &= toclear - 1;
                    atomicSub(&colcnt[w * 32 + bp], 1);
                }
                if (keep && !(word & keep)) atomicAdd(&colcnt[mg], 1);
                Msh[q][w] = keep;
            }
        }
        if (hasOvf) {
            for (int q = tid; q < NQ; q += K3_BS) {
                if (cidx[q] != -2) continue;
                int k = n_q[q];
                float mv = fmut(costT[q], k); int mg = 0;
                for (int g = 1; g < NG; ++g) {
                    float v = fmut(costT[(size_t)g * NQ + q], k);
                    if (v < mv) { mv = v; mg = g; }
                }
                int keepw = mg >> 5;
                uint32_t keepb = 1u << (mg & 31);
                for (int w = 0; w < 4; ++w) {
                    uint32_t word = Msh[q][w];
                    uint32_t keep = (w == keepw) ? keepb : 0u;
                    uint32_t toclear = word & ~keep;
                    while (toclear) {
                        int bp = __ffs(toclear) - 1;
                        toclear &= toclear - 1;
                        atomicSub(&colcnt[w * 32 + bp], 1);
                    }
                    if (keep && !(word & keep)) atomicAdd(&colcnt[mg], 1);
                    Msh[q][w] = keep;
                }
            }
        }
        __syncthreads();  // B4

        // P5: loop condition
        if (tid < NG && colcnt[tid] == 0) flags[0] = 1;
        __syncthreads();  // B5
    }

    // matched_qid: argmin_q of (M ? mutated cost : 1e30)
    for (int g = wave; g < NG; g += NW3) {
        int word = g >> 5;
        uint32_t bit = 1u << (g & 31);
        const float* col = costT + (size_t)g * NQ;
        float mv = INFINITY; int mi = 0x7fffffff;
        for (int q = lane; q < NQ; q += 64) {
            float v = 1e30f;
            if (Msh[q][word] & bit) {
                int c = cidx[q];
                v = (c >= 0) ? crow[c][g] : fmut(col[q], n_q[q]);
            }
            if (v < mv || (v == mv && q < mi)) { mv = v; mi = q; }
        }
        for (int off = 1; off < 64; off <<= 1) {
            float ov = __shfl_xor(mv, off); int oi = __shfl_xor(mi, off);
            if (ov < mv || (ov == mv && oi < mi)) { mv = ov; mi = oi; }
        }
        if (lane == 0) mqOut[g] = (float)mi;
    }
    // selected / gt_idx
    for (int q = tid; q < NQ; q += K3_BS) {
        uint4 m = *reinterpret_cast<const uint4*>(&Msh[q][0]);
        selOut[q] = (m.x | m.y | m.z | m.w) ? 1.0f : 0.0f;
        int gi = 0;
        if (m.x) gi = __ffs(m.x) - 1;
        else if (m.y) gi = 32 + __ffs(m.y) - 1;
        else if (m.z) gi = 64 + __ffs(m.z) - 1;
        else if (m.w) gi = 96 + __ffs(m.w) - 1;
        gtiOut[q] = (float)gi;
    }
    __syncthreads();  // all costT reads done before overwrite
    for (int i = tid; i < NQ * NG; i += K3_BS) {
        int q = i / NG;
        int g = i - q * NG;
        costT[i] = (Msh[q][g >> 5] & (1u << (g & 31))) ? 1.0f : 0.0f;
    }
}

extern "C" void kernel_launch(void* const* d_in, const int* in_sizes, int n_in,
                              void* d_out, int out_size, void* d_ws, size_t ws_size,
                              hipStream_t stream) {
    const float* logits = (const float*)d_in[0];
    const float* pboxes = (const float*)d_in[1];
    const float* gboxes = (const float*)d_in[2];
    const int* labels = (const int*)d_in[3];
    const float* img = (const float*)d_in[4];
    float* out = (float*)d_out;
    float* lists = (float*)d_ws;  // BATCH*NG*13 floats = 83.2 KB

    fgcost_kernel<<<K1_BLOCKS, 256, 0, stream>>>(logits, pboxes, gboxes, labels, img, out + OFF_M);
    init_kernel<<<525, 256, 0, stream>>>(pboxes, gboxes, img, out + OFF_M, lists, out + OFF_GTI);
    match_kernel<<<BATCH, K3_BS, 0, stream>>>(lists, out);
}

// Round 6
// 148.931 us; speedup vs baseline: 2.5590x; 1.2472x over previous
//
#include <hip/hip_runtime.h>
#include <stdint.h>

#define BATCH 16
#define NQ 2000
#define NC 80
#define NG 100
#define MAX_ITERS 1000
#define MAXC 96
#define QT 64
#define TILES 32                     // ceil(2000/64)
#define K1_BLOCKS (BATCH * TILES)    // 512
#define K3_BS 1024
#define NW3 16
#define NCAND 12
#define LSTRIDE 13                   // k + 12 candidate indices

// output layout (floats)
#define OFF_SEL 0
#define OFF_GTI (BATCH * NQ)                 // 32000
#define OFF_MQ (2 * BATCH * NQ)              // 64000
#define OFF_M (2 * BATCH * NQ + BATCH * NG)  // 65600

// exact replay of the reference's sequential in-place +1e5 adds
__device__ __forceinline__ float fmut(float c, int k) {
    for (int i = 0; i < k; ++i) c += 100000.0f;
    return c;
}

__device__ __forceinline__ bool lexlt(float v1, int i1, float v2, int i2) {
    return (v1 < v2) | ((v1 == v2) & (i1 < i2));
}

// branchless compare-exchange ascending between slots a<b of (val,idx) arrays
#define CE(vv, ii, a, b) do { \
    bool t_ = lexlt(vv[b], ii[b], vv[a], ii[a]); \
    float lo_ = t_ ? vv[b] : vv[a]; float hi_ = t_ ? vv[a] : vv[b]; \
    int loi_ = t_ ? ii[b] : ii[a]; int hii_ = t_ ? ii[a] : ii[b]; \
    vv[a] = lo_; vv[b] = hi_; ii[a] = loi_; ii[b] = hii_; \
} while (0)

// =================== K1: fused fg + cost, tiled, transposed write ===================
__global__ __launch_bounds__(256) void fgcost_kernel(
    const float* __restrict__ logits, const float* __restrict__ pred_boxes,
    const float* __restrict__ gt_boxes, const int* __restrict__ labels,
    const float* __restrict__ img_sz, float* __restrict__ costT_all) {
    const int tid = threadIdx.x;
    const int b = blockIdx.x / TILES;
    const int tile = blockIdx.x - b * TILES;
    const int q0 = tile * QT;

    __shared__ float ct[QT][NG + 1];
    __shared__ float s_rx1[NG], s_ry1[NG], s_rx2[NG], s_ry2[NG];
    __shared__ float s_clx[NG], s_chx[NG], s_cly[NG], s_chy[NG];
    __shared__ float s_gx1[NG], s_gy1[NG], s_gx2[NG], s_gy2[NG];
    __shared__ float s_d1[NG], s_d2[NG], s_d3[NG], s_d4[NG];
    __shared__ float s_ga[NG];
    __shared__ int s_lab[NG];
    __shared__ float pbx[QT][11];
    __shared__ unsigned fgm[QT];

    const float i0 = img_sz[b * 4 + 0], i1 = img_sz[b * 4 + 1];
    const float i2 = img_sz[b * 4 + 2], i3 = img_sz[b * 4 + 3];

    if (tid < NG) {
        const float4 gt = *reinterpret_cast<const float4*>(gt_boxes + (b * NG + tid) * 4);
        float GX1 = (gt.x - 0.5f * gt.z) * i0, GY1 = (gt.y - 0.5f * gt.w) * i1;
        float GX2 = (gt.x + 0.5f * gt.z) * i2, GY2 = (gt.y + 0.5f * gt.w) * i3;
        float tcx = (GX1 + GX2) * 0.5f, tcy = (GY1 + GY2) * 0.5f;
        float tw = GX2 - GX1, th = GY2 - GY1;
        float X1 = tcx - 0.5f * tw, Y1 = tcy - 0.5f * th;
        float X2 = tcx + 0.5f * tw, Y2 = tcy + 0.5f * th;
        float w_ = X2 - X1, h_ = Y2 - Y1;
        s_rx1[tid] = X1; s_ry1[tid] = Y1; s_rx2[tid] = X2; s_ry2[tid] = Y2;
        s_clx[tid] = tcx - 2.5f * w_; s_chx[tid] = tcx + 2.5f * w_;
        s_cly[tid] = tcy - 2.5f * h_; s_chy[tid] = tcy + 2.5f * h_;
        s_gx1[tid] = GX1; s_gy1[tid] = GY1; s_gx2[tid] = GX2; s_gy2[tid] = GY2;
        s_d1[tid] = GX1 / i0; s_d2[tid] = GY1 / i1; s_d3[tid] = GX2 / i2; s_d4[tid] = GY2 / i3;
        s_ga[tid] = (GX2 - GX1) * (GY2 - GY1);
        s_lab[tid] = labels[b * NG + tid];
    }
    if (tid < QT) {
        fgm[tid] = 0;
        int q = q0 + tid;
        if (q < NQ) {
            const float4 pb = *reinterpret_cast<const float4*>(pred_boxes + (size_t)(b * NQ + q) * 4);
            float x1 = (pb.x - 0.5f * pb.z) * i0, y1 = (pb.y - 0.5f * pb.w) * i1;
            float x2 = (pb.x + 0.5f * pb.z) * i2, y2 = (pb.y + 0.5f * pb.w) * i3;
            pbx[tid][0] = x1; pbx[tid][1] = y1; pbx[tid][2] = x2; pbx[tid][3] = y2;
            pbx[tid][4] = (x1 + x2) * 0.5f; pbx[tid][5] = (y1 + y2) * 0.5f;
            pbx[tid][6] = x1 / i0; pbx[tid][7] = y1 / i1; pbx[tid][8] = x2 / i2; pbx[tid][9] = y2 / i3;
            pbx[tid][10] = (x2 - x1) * (y2 - y1);
        }
    }
    __syncthreads();

    // fg: 4-way split over g per q
    {
        int ql = tid & 63, part = tid >> 6;
        if (q0 + ql < NQ) {
            float ax = pbx[ql][4], ay = pbx[ql][5];
            bool any = false;
            for (int g = part * 25; g < part * 25 + 25; ++g) {
                bool in_box = (ax > s_rx1[g]) && (ax < s_rx2[g]) && (ay > s_ry1[g]) && (ay < s_ry2[g]);
                bool in_ctr = (ax > s_clx[g]) && (ax < s_chx[g]) && (ay > s_cly[g]) && (ay < s_chy[g]);
                any = any || in_box || in_ctr;
            }
            if (any) atomicOr(&fgm[ql], 1u);
        }
    }
    __syncthreads();

    for (int e = 0; e < QT * NG / 256; ++e) {
        int idx = e * 256 + tid;
        int ql = idx / NG, g = idx - ql * NG;
        int q = q0 + ql;
        if (q < NQ) {
            float x1 = pbx[ql][0], y1 = pbx[ql][1], x2 = pbx[ql][2], y2 = pbx[ql][3];
            float ax = pbx[ql][4], ay = pbx[ql][5];
            bool in_box = (ax > s_rx1[g]) && (ax < s_rx2[g]) && (ay > s_ry1[g]) && (ay < s_ry2[g]);
            bool in_ctr = (ax > s_clx[g]) && (ax < s_chx[g]) && (ay > s_cly[g]) && (ay < s_chy[g]);
            bool in_bc = in_box && in_ctr;
            bool fgb = fgm[ql] != 0;

            float lg = logits[(size_t)(b * NQ + q) * NC + s_lab[g]];
            float p = 1.0f / (1.0f + expf(-lg));
            float neg = 0.75f * (p * p) * (-logf(1.0f - p + 1e-8f));
            float pos = 0.25f * ((1.0f - p) * (1.0f - p)) * (-logf(p + 1e-8f));
            float cc = pos - neg;

            float cb = fabsf(pbx[ql][6] - s_d1[g]);
            cb = cb + fabsf(pbx[ql][7] - s_d2[g]);
            cb = cb + fabsf(pbx[ql][8] - s_d3[g]);
            cb = cb + fabsf(pbx[ql][9] - s_d4[g]);

            float aA = pbx[ql][10];
            float GX1 = s_gx1[g], GY1 = s_gy1[g], GX2 = s_gx2[g], GY2 = s_gy2[g];
            float lx = fmaxf(x1, GX1), ly = fmaxf(y1, GY1);
            float rx = fminf(x2, GX2), ry = fminf(y2, GY2);
            float iw = fmaxf(rx - lx, 0.0f), ih = fmaxf(ry - ly, 0.0f);
            float inter = iw * ih;
            float uni = aA + s_ga[g] - inter;
            float iou = inter / uni;
            float hx1 = fminf(x1, GX1), hy1 = fminf(y1, GY1);
            float hx2 = fmaxf(x2, GX2), hy2 = fmaxf(y2, GY2);
            float hw = fmaxf(hx2 - hx1, 0.0f), hh = fmaxf(hy2 - hy1, 0.0f);
            float harea = hw * hh;
            float giou = iou - (harea - uni) / harea;

            float cost = 5.0f * cb;
            cost = cost + 2.0f * cc;
            cost = cost + 2.0f * (-giou);
            cost = cost + (in_bc ? 0.0f : 100.0f);
            cost = cost + (fgb ? 0.0f : 10000.0f);
            ct[ql][g] = cost;
        }
    }
    __syncthreads();

    float* dst = costT_all + (size_t)b * NQ * NG;
    for (int e = 0; e < QT * NG / 256; ++e) {
        int idx = e * 256 + tid;
        int g = idx >> 6, ql = idx & 63;
        int q = q0 + ql;
        if (q < NQ) dst[(size_t)g * NQ + q] = ct[ql][g];
    }
}

// =================== K2: dynk + bottom-12 (blocks 0..399) | rowargmin (blocks 400..524) ===================
__global__ __launch_bounds__(256) void init_kernel(const float* __restrict__ pred_boxes,
                                                   const float* __restrict__ gt_boxes,
                                                   const float* __restrict__ img_sz,
                                                   const float* __restrict__ costT_all,
                                                   float* __restrict__ lists,
                                                   float* __restrict__ rowamin) {
    const int tid = threadIdx.x;
    if (blockIdx.x >= 400) {
        // rowargmin: one thread per (b,q)
        int gtid = (blockIdx.x - 400) * 256 + tid;
        if (gtid < BATCH * NQ) {
            int b = gtid / NQ, q = gtid - b * NQ;
            const float* base = costT_all + (size_t)b * NQ * NG + q;
            float mv = base[0]; int mg = 0;
            for (int g = 1; g < NG; ++g) {
                float v = base[(size_t)g * NQ];
                if (v < mv) { mv = v; mg = g; }
            }
            rowamin[gtid] = (float)mg;
        }
        return;
    }
    // dynk + bottom-12: one wave per (b,g); branchless sorting networks
    int w = blockIdx.x * 4 + (tid >> 6);
    int lane = tid & 63;
    int b = w / NG, g = w - b * NG;

    const float i0 = img_sz[b * 4 + 0], i1 = img_sz[b * 4 + 1];
    const float i2 = img_sz[b * 4 + 2], i3 = img_sz[b * 4 + 3];
    const float4 gt = *reinterpret_cast<const float4*>(gt_boxes + (b * NG + g) * 4);
    float GX1 = (gt.x - 0.5f * gt.z) * i0, GY1 = (gt.y - 0.5f * gt.w) * i1;
    float GX2 = (gt.x + 0.5f * gt.z) * i2, GY2 = (gt.y + 0.5f * gt.w) * i3;
    float GA = (GX2 - GX1) * (GY2 - GY1);

    const float* pbox = pred_boxes + (size_t)b * NQ * 4;
    const float* col = costT_all + (size_t)b * NQ * NG + (size_t)g * NQ;

    // per-lane sorted lists: bottom-12 of (cost,q) ; bottom-5 of (-iou,q)
    float va[12]; int ia[12];
    float tv[5]; int ti[5];
#pragma unroll
    for (int j = 0; j < 12; ++j) { va[j] = INFINITY; ia[j] = 0x7fffffff; }
#pragma unroll
    for (int j = 0; j < 5; ++j) { tv[j] = INFINITY; ti[j] = 0x7fffffff; }

    for (int q = lane; q < NQ; q += 64) {
        const float4 pb = *reinterpret_cast<const float4*>(pbox + q * 4);
        float cv = col[q];
        float x1 = (pb.x - 0.5f * pb.z) * i0, y1 = (pb.y - 0.5f * pb.w) * i1;
        float x2 = (pb.x + 0.5f * pb.z) * i2, y2 = (pb.y + 0.5f * pb.w) * i3;
        float aA = (x2 - x1) * (y2 - y1);
        float lx = fmaxf(x1, GX1), ly = fmaxf(y1, GY1);
        float rx = fminf(x2, GX2), ry = fminf(y2, GY2);
        float iw = fmaxf(rx - lx, 0.0f), ih = fmaxf(ry - ly, 0.0f);
        float inter = iw * ih;
        float uni = aA + GA - inter;
        float niou = -(inter / uni);

        // branchless insert (niou,q) into sorted-5
        {
            bool ins = lexlt(niou, q, tv[4], ti[4]);
            tv[4] = ins ? niou : tv[4]; ti[4] = ins ? q : ti[4];
            CE(tv, ti, 3, 4); CE(tv, ti, 2, 3); CE(tv, ti, 1, 2); CE(tv, ti, 0, 1);
        }
        // branchless insert (cv,q) into sorted-12
        {
            bool ins = lexlt(cv, q, va[11], ia[11]);
            va[11] = ins ? cv : va[11]; ia[11] = ins ? q : ia[11];
            CE(va, ia, 10, 11); CE(va, ia, 9, 10); CE(va, ia, 8, 9); CE(va, ia, 7, 8);
            CE(va, ia, 6, 7); CE(va, ia, 5, 6); CE(va, ia, 4, 5); CE(va, ia, 3, 4);
            CE(va, ia, 2, 3); CE(va, ia, 1, 2); CE(va, ia, 0, 1);
        }
    }

    // butterfly bitonic merge: bottom-12 (pad-16 network)
#pragma unroll
    for (int off = 1; off < 64; off <<= 1) {
        float bv[12]; int bi[12];
#pragma unroll
        for (int j = 0; j < 12; ++j) { bv[j] = __shfl_xor(va[j], off, 64); bi[j] = __shfl_xor(ia[j], off, 64); }
        float mv[16]; int mi[16];
#pragma unroll
        for (int j = 0; j < 4; ++j) { mv[j] = va[j]; mi[j] = ia[j]; }
#pragma unroll
        for (int j = 4; j < 12; ++j) {
            bool t = lexlt(bv[15 - j], bi[15 - j], va[j], ia[j]);
            mv[j] = t ? bv[15 - j] : va[j]; mi[j] = t ? bi[15 - j] : ia[j];
        }
#pragma unroll
        for (int j = 12; j < 16; ++j) { mv[j] = bv[15 - j]; mi[j] = bi[15 - j]; }
#pragma unroll
        for (int d = 8; d >= 1; d >>= 1) {
#pragma unroll
            for (int i = 0; i < 16; ++i) {
                if ((i & d) == 0) CE(mv, mi, i, (i | d));
            }
        }
#pragma unroll
        for (int j = 0; j < 12; ++j) { va[j] = mv[j]; ia[j] = mi[j]; }
    }

    // butterfly bitonic merge: bottom-5 of -iou (pad-8 network)
#pragma unroll
    for (int off = 1; off < 64; off <<= 1) {
        float bv[5]; int bi[5];
#pragma unroll
        for (int j = 0; j < 5; ++j) { bv[j] = __shfl_xor(tv[j], off, 64); bi[j] = __shfl_xor(ti[j], off, 64); }
        float mv[8]; int mi[8];
#pragma unroll
        for (int j = 0; j < 3; ++j) { mv[j] = tv[j]; mi[j] = ti[j]; }
#pragma unroll
        for (int j = 3; j < 5; ++j) {
            bool t = lexlt(bv[7 - j], bi[7 - j], tv[j], ti[j]);
            mv[j] = t ? bv[7 - j] : tv[j]; mi[j] = t ? bi[7 - j] : ti[j];
        }
#pragma unroll
        for (int j = 5; j < 8; ++j) { mv[j] = bv[7 - j]; mi[j] = bi[7 - j]; }
#pragma unroll
        for (int d = 4; d >= 1; d >>= 1) {
#pragma unroll
            for (int i = 0; i < 8; ++i) {
                if ((i & d) == 0) CE(mv, mi, i, (i | d));
            }
        }
#pragma unroll
        for (int j = 0; j < 5; ++j) { tv[j] = mv[j]; ti[j] = mi[j]; }
    }

    if (lane == 0) {
        // sum of top-5 IoU in descending order == -(tv0+tv1+tv2+tv3+tv4) (negation exact)
        float s = -((((tv[0] + tv[1]) + tv[2]) + tv[3]) + tv[4]);
        int k = (int)s;
        if (k < 1) k = 1;
        float* o = lists + (size_t)w * LSTRIDE;
        o[0] = (float)k;
        o[1] = (float)ia[0]; o[2] = (float)ia[1]; o[3] = (float)ia[2]; o[4] = (float)ia[3];
        o[5] = (float)ia[4]; o[6] = (float)ia[5]; o[7] = (float)ia[6]; o[8] = (float)ia[7];
        o[9] = (float)ia[8]; o[10] = (float)ia[9]; o[11] = (float)ia[10]; o[12] = (float)ia[11];
    }
}

// =================== K3: per-batch dynamic-k matching ===================
__global__ __launch_bounds__(K3_BS) void match_kernel(const float* __restrict__ lists,
                                                      float* __restrict__ out) {
    const int b = blockIdx.x;
    const int tid = threadIdx.x;
    const int wave = tid >> 6;
    const int lane = tid & 63;

    __shared__ uint32_t Msh[NQ][4];        // 32 KB
    __shared__ float crow[MAXC][NG + 1];   // 38.8 KB padded
    __shared__ int n_q[NQ];                // 8 KB
    __shared__ int16_t cidx[NQ];           // 4 KB  (-1 none, >=0 cached conf0, -2 uncached conf0)
    __shared__ int candq[NG][NCAND];       // 4.8 KB
    __shared__ uint8_t slotM[MAXC];
    __shared__ int crowq[MAXC];
    __shared__ int colcnt[NG];
    __shared__ int needscan[NG];
    __shared__ int flags[2];               // [0]=any col unmatched, [1]=has_conf
    __shared__ int nconf0, nscan;

    float* costT = out + OFF_M + (size_t)b * NQ * NG;
    float* selOut = out + OFF_SEL + b * NQ;
    float* gtiOut = out + OFF_GTI + b * NQ;
    const float* rowamin_b = out + OFF_GTI + b * NQ;
    float* mqOut = out + OFF_MQ + b * NG;

    if (tid == 0) { flags[0] = 0; flags[1] = 0; nconf0 = 0; nscan = 0; }
    for (int q = tid; q < NQ; q += K3_BS) {
        Msh[q][0] = 0; Msh[q][1] = 0; Msh[q][2] = 0; Msh[q][3] = 0;
        cidx[q] = -1; n_q[q] = 0;
    }
    __syncthreads();

    // build M + colcnt + candidate lists
    if (tid < NG) {
        const float* o = lists + (size_t)(b * NG + tid) * LSTRIDE;
        int k = (int)o[0];
        int word = tid >> 5;
        uint32_t bit = 1u << (tid & 31);
        for (int j = 0; j < NCAND; ++j) candq[tid][j] = (int)o[1 + j];
        for (int j = 0; j < 5; ++j)
            if (j < k) atomicOr(&Msh[candq[tid][j]][word], bit);
        colcnt[tid] = k;
    }
    __syncthreads();

    // conflict0 rows -> onehot(precomputed row argmin)
    for (int q = tid; q < NQ; q += K3_BS) {
        uint4 m = *reinterpret_cast<const uint4*>(&Msh[q][0]);
        int pc = __popc(m.x) + __popc(m.y) + __popc(m.z) + __popc(m.w);
        if (pc > 1) {
            int slot = atomicAdd(&nconf0, 1);
            int c = (slot < MAXC) ? slot : -1;
            cidx[q] = (c >= 0) ? (int16_t)c : (int16_t)-2;
            if (c >= 0) crowq[c] = q;
            int mg = (int)rowamin_b[q];
            uint32_t words[4] = {m.x, m.y, m.z, m.w};
            for (int w = 0; w < 4; ++w) {
                uint32_t word = words[w];
                while (word) {
                    int bp = __ffs(word) - 1;
                    word &= word - 1;
                    atomicSub(&colcnt[w * 32 + bp], 1);
                }
                Msh[q][w] = 0;
            }
            Msh[q][mg >> 5] = 1u << (mg & 31);
            atomicAdd(&colcnt[mg], 1);
        }
    }
    __syncthreads();

    const int ncached = (nconf0 < MAXC) ? nconf0 : MAXC;
    const bool hasOvf = nconf0 > MAXC;
    for (int i = tid; i < ncached * NG; i += K3_BS) {
        int c = i / NG, g = i - c * NG;
        crow[c][g] = costT[(size_t)g * NQ + crowq[c]];
    }
    if (tid < NG && colcnt[tid] == 0) flags[0] = 1;
    __syncthreads();

    // ---------------- while loop ----------------
    for (int it = 0; it < MAX_ITERS; ++it) {
        if (!flags[0]) break;

        // P1: matched-at-entry -> n_q++; mark cached rows
        for (int q = tid; q < NQ; q += K3_BS) {
            uint4 m = *reinterpret_cast<const uint4*>(&Msh[q][0]);
            bool mm = (m.x | m.y | m.z | m.w) != 0;
            if (mm) n_q[q]++;
            int c = cidx[q];
            if (c >= 0) slotM[c] = mm ? 1 : 0;
        }
        __syncthreads();  // B1

        // P1b: replay +1e5 on cached matched rows
        for (int i = tid; i < ncached * NG; i += K3_BS) {
            int c = i / NG, g = i - c * NG;
            if (slotM[c]) crow[c][g] += 100000.0f;
        }
        // P2a: candidate fast path — first bottom-12 candidate with n==0 is the exact argmin
        if (tid < NG && colcnt[tid] == 0) {
            int g = tid;
            int win = -1;
            for (int j = 0; j < NCAND; ++j) {
                int qi = candq[g][j];
                if (n_q[qi] == 0) { win = qi; break; }
            }
            if (win >= 0) {
                atomicOr(&Msh[win][g >> 5], 1u << (g & 31));
                colcnt[g] = 1;
            } else {
                needscan[atomicAdd(&nscan, 1)] = g;
            }
        }
        __syncthreads();  // B2

        int ns = nscan;
        if (ns > 0) {
            for (int s = wave; s < ns; s += NW3) {
                int g = needscan[s];
                const float* col = costT + (size_t)g * NQ;
                float mv = INFINITY; int mi = 0x7fffffff;
                for (int q = lane; q < NQ; q += 64) {
                    if (n_q[q] == 0) {
                        float v = col[q];
                        if (v < mv || (v == mv && q < mi)) { mv = v; mi = q; }
                    }
                }
                for (int off = 1; off < 64; off <<= 1) {
                    float ov = __shfl_xor(mv, off); int oi = __shfl_xor(mi, off);
                    if (ov < mv || (ov == mv && oi < mi)) { mv = ov; mi = oi; }
                }
                if (mi == 0x7fffffff) {  // every row penalized -> exact replay
                    for (int q = lane; q < NQ; q += 64) {
                        float v = fmut(col[q], n_q[q]);
                        if (v < mv || (v == mv && q < mi)) { mv = v; mi = q; }
                    }
                    for (int off = 1; off < 64; off <<= 1) {
                        float ov = __shfl_xor(mv, off); int oi = __shfl_xor(mi, off);
                        if (ov < mv || (ov == mv && oi < mi)) { mv = ov; mi = oi; }
                    }
                }
                if (lane == 0) {
                    atomicOr(&Msh[mi][g >> 5], 1u << (g & 31));
                    colcnt[g] = 1;
                }
            }
            __syncthreads();  // B2b (ns uniform)
        }

        // P3: has_conf
        for (int q = tid; q < NQ; q += K3_BS) {
            uint4 m = *reinterpret_cast<const uint4*>(&Msh[q][0]);
            int pc = __popc(m.x) + __popc(m.y) + __popc(m.z) + __popc(m.w);
            if (pc > 1) flags[1] = 1;
        }
        __syncthreads();  // B3
        int hc = flags[1];
        __syncthreads();  // B3b — all reads done before reset
        if (!hc) break;   // no conflict -> all columns matched -> loop would exit

        if (tid == 0) { flags[1] = 0; nscan = 0; flags[0] = 0; }
        // P4: reset ALL conflict0 rows to onehot(argmin of current mutated row)
        for (int c = tid; c < ncached; c += K3_BS) {
            int q = crowq[c];
            float mv = crow[c][0]; int mg = 0;
            for (int g = 1; g < NG; ++g) { float v = crow[c][g]; if (v < mv) { mv = v; mg = g; } }
            int keepw = mg >> 5;
            uint32_t keepb = 1u << (mg & 31);
            for (int w = 0; w < 4; ++w) {
                uint32_t word = Msh[q][w];
                uint32_t keep = (w == keepw) ? keepb : 0u;
                uint32_t toclear = word & ~keep;
                while (toclear) {
                    int bp = __ffs(toclear) - 1;
                    toclear &= toclear - 1;
                    atomicSub(&colcnt[w * 32 + bp], 1);
                }
                if (keep && !(word & keep)) atomicAdd(&colcnt[mg], 1);
                Msh[q][w] = keep;
            }
        }
        if (hasOvf) {
            for (int q = tid; q < NQ; q += K3_BS) {
                if (cidx[q] != -2) continue;
                int k = n_q[q];
                float mv = fmut(costT[q], k); int mg = 0;
                for (int g = 1; g < NG; ++g) {
                    float v = fmut(costT[(size_t)g * NQ + q], k);
                    if (v < mv) { mv = v; mg = g; }
                }
                int keepw = mg >> 5;
                uint32_t keepb = 1u << (mg & 31);
                for (int w = 0; w < 4; ++w) {
                    uint32_t word = Msh[q][w];
                    uint32_t keep = (w == keepw) ? keepb : 0u;
                    uint32_t toclear = word & ~keep;
                    while (toclear) {
                        int bp = __ffs(toclear) - 1;
                        toclear &= toclear - 1;
                        atomicSub(&colcnt[w * 32 + bp], 1);
                    }
                    if (keep && !(word & keep)) atomicAdd(&colcnt[mg], 1);
                    Msh[q][w] = keep;
                }
            }
        }
        __syncthreads();  // B4

        // P5: loop condition
        if (tid < NG && colcnt[tid] == 0) flags[0] = 1;
        __syncthreads();  // B5
    }

    // matched_qid: argmin_q of (M ? mutated cost : 1e30)
    for (int g = wave; g < NG; g += NW3) {
        int word = g >> 5;
        uint32_t bit = 1u << (g & 31);
        const float* col = costT + (size_t)g * NQ;
        float mv = INFINITY; int mi = 0x7fffffff;
        for (int q = lane; q < NQ; q += 64) {
            float v = 1e30f;
            if (Msh[q][word] & bit) {
                int c = cidx[q];
                v = (c >= 0) ? crow[c][g] : fmut(col[q], n_q[q]);
            }
            if (v < mv || (v == mv && q < mi)) { mv = v; mi = q; }
        }
        for (int off = 1; off < 64; off <<= 1) {
            float ov = __shfl_xor(mv, off); int oi = __shfl_xor(mi, off);
            if (ov < mv || (ov == mv && oi < mi)) { mv = ov; mi = oi; }
        }
        if (lane == 0) mqOut[g] = (float)mi;
    }
    // selected / gt_idx
    for (int q = tid; q < NQ; q += K3_BS) {
        uint4 m = *reinterpret_cast<const uint4*>(&Msh[q][0]);
        selOut[q] = (m.x | m.y | m.z | m.w) ? 1.0f : 0.0f;
        int gi = 0;
        if (m.x) gi = __ffs(m.x) - 1;
        else if (m.y) gi = 32 + __ffs(m.y) - 1;
        else if (m.z) gi = 64 + __ffs(m.z) - 1;
        else if (m.w) gi = 96 + __ffs(m.w) - 1;
        gtiOut[q] = (float)gi;
    }
    __syncthreads();  // all costT reads done before overwrite
    for (int i = tid; i < NQ * NG; i += K3_BS) {
        int q = i / NG;
        int g = i - q * NG;
        costT[i] = (Msh[q][g >> 5] & (1u << (g & 31))) ? 1.0f : 0.0f;
    }
}

extern "C" void kernel_launch(void* const* d_in, const int* in_sizes, int n_in,
                              void* d_out, int out_size, void* d_ws, size_t ws_size,
                              hipStream_t stream) {
    const float* logits = (const float*)d_in[0];
    const float* pboxes = (const float*)d_in[1];
    const float* gboxes = (const float*)d_in[2];
    const int* labels = (const int*)d_in[3];
    const float* img = (const float*)d_in[4];
    float* out = (float*)d_out;
    float* lists = (float*)d_ws;  // BATCH*NG*13 floats = 83.2 KB

    fgcost_kernel<<<K1_BLOCKS, 256, 0, stream>>>(logits, pboxes, gboxes, labels, img, out + OFF_M);
    init_kernel<<<525, 256, 0, stream>>>(pboxes, gboxes, img, out + OFF_M, lists, out + OFF_GTI);
    match_kernel<<<BATCH, K3_BS, 0, stream>>>(lists, out);
}